// Round 1
// baseline (108863.879 us; speedup 1.0000x reference)
//
#include <hip/hip_runtime.h>
#include <math.h>

#define T_STEPS 20000
#define RSIZE   2048
#define ISIZE   128
#define NBLK    64
#define NTHR    512                    // 8 waves/block
#define NWAVES  (NBLK * (NTHR / 64))   // 512 waves
#define RPW     (RSIZE / NWAVES)       // 4 rows per wave

// ---- cheap erf: Abramowitz-Stegun 7.1.26, |err| <= 1.5e-7 (abs) ----
__device__ __forceinline__ float erf_approx(float x) {
    float ax = fabsf(x);
    float t  = 1.0f / (1.0f + 0.3275911f * ax);
    float y  = t * (0.254829592f +
               t * (-0.284496736f +
               t * (1.421413741f +
               t * (-1.453152027f +
               t * 1.061405429f))));
    float e  = __expf(-ax * ax);
    float r  = 1.0f - y * e;
    return copysignf(r, x);
}

// ---- device-scope grid barrier (gen-counter, sense-free) ----
__device__ __forceinline__ void grid_barrier(unsigned* counter, unsigned* gen,
                                             unsigned nblocks) {
    __syncthreads();
    if (threadIdx.x == 0) {
        unsigned g = __hip_atomic_load(gen, __ATOMIC_RELAXED,
                                       __HIP_MEMORY_SCOPE_AGENT);
        unsigned arrived = __hip_atomic_fetch_add(counter, 1u, __ATOMIC_ACQ_REL,
                                                  __HIP_MEMORY_SCOPE_AGENT);
        if (arrived == nblocks - 1u) {
            __hip_atomic_store(counter, 0u, __ATOMIC_RELAXED,
                               __HIP_MEMORY_SCOPE_AGENT);
            __hip_atomic_store(gen, g + 1u, __ATOMIC_RELEASE,
                               __HIP_MEMORY_SCOPE_AGENT);
        } else {
            while (__hip_atomic_load(gen, __ATOMIC_ACQUIRE,
                                     __HIP_MEMORY_SCOPE_AGENT) == g) {
                __builtin_amdgcn_s_sleep(1);
            }
        }
    }
    __syncthreads();
}

__global__ __launch_bounds__(NTHR) void esn_persistent(
        const float* __restrict__ input,   // [T, 128]
        const float* __restrict__ W_in,    // [2048, 128]
        const float* __restrict__ W_res,   // [2048, 2048]
        float* __restrict__ out,           // [T, 2048]  (rows == states)
        unsigned* __restrict__ bar) {
    __shared__ float xbuf[RSIZE];   // x[t-1]
    __shared__ float ubuf[ISIZE];   // input[t]

    const int tid  = threadIdx.x;
    const int lane = tid & 63;
    const int wv   = tid >> 6;
    const int wid  = blockIdx.x * (NTHR / 64) + wv;
    const int r0   = wid * RPW;
    const float invs = 0.022097086912079608f;  // 1/sqrt(2048)

    // ---- persistent weights in VGPRs ----
    // W_res row r, lane l holds cols {c*256 + l*4 .. +3 : c=0..7}  (32 f32)
    float4 wr[RPW][8];
    float2 wi[RPW];
#pragma unroll
    for (int m = 0; m < RPW; ++m) {
        const float* row = W_res + (size_t)(r0 + m) * RSIZE;
#pragma unroll
        for (int c = 0; c < 8; ++c)
            wr[m][c] = *(const float4*)(row + c * 256 + lane * 4);
        wi[m] = *(const float2*)(W_in + (size_t)(r0 + m) * ISIZE + lane * 2);
    }

    unsigned* counter = bar;
    unsigned* gen     = bar + 32;  // separate 128B line

    for (int t = 0; t < T_STEPS; ++t) {
        // ---- stage x[t-1] and u[t] into LDS ----
        if (t == 0) {
            ((float4*)xbuf)[tid] = make_float4(0.f, 0.f, 0.f, 0.f);
        } else {
            ((float4*)xbuf)[tid] =
                *(const float4*)(out + (size_t)(t - 1) * RSIZE + tid * 4);
        }
        if (tid < ISIZE / 4) {
            ((float4*)ubuf)[tid] =
                *(const float4*)(input + (size_t)t * ISIZE + tid * 4);
        }
        __syncthreads();

        // ---- per-wave matvec rows r0..r0+3 ----
        float4 xv[8];
#pragma unroll
        for (int c = 0; c < 8; ++c)
            xv[c] = ((const float4*)xbuf)[c * 64 + lane];
        float2 uv = ((const float2*)ubuf)[lane];

        float acc[RPW];
#pragma unroll
        for (int m = 0; m < RPW; ++m) {
            float a = wi[m].x * uv.x + wi[m].y * uv.y;
#pragma unroll
            for (int c = 0; c < 8; ++c) {
                a += wr[m][c].x * xv[c].x;
                a += wr[m][c].y * xv[c].y;
                a += wr[m][c].z * xv[c].z;
                a += wr[m][c].w * xv[c].w;
            }
#pragma unroll
            for (int off = 32; off > 0; off >>= 1)
                a += __shfl_xor(a, off, 64);
            acc[m] = a;   // every lane now holds the full row sum
        }

        // lanes 0..3 each finish one row (static acc indexing, rule #20)
        if (lane < RPW) {
            float pre = (lane == 0) ? acc[0]
                      : (lane == 1) ? acc[1]
                      : (lane == 2) ? acc[2] : acc[3];
            float xp  = xbuf[r0 + lane];
            float xn  = 0.1f * xp + 0.9f * erf_approx(pre) * invs;
            out[(size_t)t * RSIZE + r0 + lane] = xn;
        }

        if (t + 1 < T_STEPS)
            grid_barrier(counter, gen, (unsigned)gridDim.x);
    }
}

extern "C" void kernel_launch(void* const* d_in, const int* in_sizes, int n_in,
                              void* d_out, int out_size, void* d_ws,
                              size_t ws_size, hipStream_t stream) {
    const float* input = (const float*)d_in[0];
    const float* W_in  = (const float*)d_in[1];
    const float* W_res = (const float*)d_in[2];
    float*       out   = (float*)d_out;
    unsigned*    bar   = (unsigned*)d_ws;

    // barrier state must be zero at the start of every call (deterministic)
    hipMemsetAsync(bar, 0, 256, stream);

    void* args[] = {(void*)&input, (void*)&W_in, (void*)&W_res,
                    (void*)&out, (void*)&bar};
    hipError_t err = hipLaunchCooperativeKernel(
        (const void*)esn_persistent, dim3(NBLK), dim3(NTHR), args, 0, stream);
    if (err != hipSuccess) {
        // 64 blocks / 256 CUs: trivially co-resident; plain launch fallback
        esn_persistent<<<dim3(NBLK), dim3(NTHR), 0, stream>>>(
            input, W_in, W_res, out, bar);
    }
}

// Round 2
// 102018.781 us; speedup vs baseline: 1.0671x; 1.0671x over previous
//
#include <hip/hip_runtime.h>
#include <math.h>

#define T_STEPS 20000
#define RSIZE   2048
#define ISIZE   128
#define NBLK    64
#define NTHR    512                    // 8 waves/block
#define NWAVES  (NBLK * (NTHR / 64))   // 512 waves
#define RPW     (RSIZE / NWAVES)       // 4 rows per wave

// ---- cheap erf: Abramowitz-Stegun 7.1.26, |err| <= 1.5e-7 (abs) ----
__device__ __forceinline__ float erf_approx(float x) {
    float ax = fabsf(x);
    float t  = 1.0f / (1.0f + 0.3275911f * ax);
    float y  = t * (0.254829592f +
               t * (-0.284496736f +
               t * (1.421413741f +
               t * (-1.453152027f +
               t * 1.061405429f))));
    float e  = __expf(-ax * ax);
    float r  = 1.0f - y * e;
    return copysignf(r, x);
}

// ---- device-scope grid barrier (gen-counter) ----
__device__ __forceinline__ void grid_barrier(unsigned* counter, unsigned* gen,
                                             unsigned nblocks) {
    __syncthreads();
    if (threadIdx.x == 0) {
        unsigned g = __hip_atomic_load(gen, __ATOMIC_RELAXED,
                                       __HIP_MEMORY_SCOPE_AGENT);
        unsigned arrived = __hip_atomic_fetch_add(counter, 1u, __ATOMIC_ACQ_REL,
                                                  __HIP_MEMORY_SCOPE_AGENT);
        if (arrived == nblocks - 1u) {
            __hip_atomic_store(counter, 0u, __ATOMIC_RELAXED,
                               __HIP_MEMORY_SCOPE_AGENT);
            __hip_atomic_store(gen, g + 1u, __ATOMIC_RELEASE,
                               __HIP_MEMORY_SCOPE_AGENT);
        } else {
            while (__hip_atomic_load(gen, __ATOMIC_ACQUIRE,
                                     __HIP_MEMORY_SCOPE_AGENT) == g) {
                __builtin_amdgcn_s_sleep(1);
            }
        }
    }
    __syncthreads();
}

// Opaque register pin: value becomes an asm output -> cannot be
// rematerialized from memory; forces true VGPR residency across the loop.
#define PIN(x) asm volatile("" : "+v"(x))

__global__ __launch_bounds__(NTHR, 2) void esn_persistent(
        const float* __restrict__ input,   // [T, 128]
        const float* __restrict__ W_in,    // [2048, 128]
        const float* __restrict__ W_res,   // [2048, 2048]
        float* __restrict__ out,           // [T, 2048]  (rows == states)
        unsigned* __restrict__ bar) {
    __shared__ float xbuf[RSIZE];   // x[t-1]
    __shared__ float ubuf[ISIZE];   // input[t]

    const int tid  = threadIdx.x;
    const int lane = tid & 63;
    const int wv   = tid >> 6;
    const int wid  = blockIdx.x * (NTHR / 64) + wv;
    const int r0   = wid * RPW;
    const float invs = 0.022097086912079608f;  // 1/sqrt(2048)

    // ---- persistent weights in VGPRs ----
    // W_res row r, lane l holds cols {c*256 + l*4 .. +3 : c=0..7}  (32 f32)
    float4 wr[RPW][8];
    float2 wi[RPW];
#pragma unroll
    for (int m = 0; m < RPW; ++m) {
        const float* row = W_res + (size_t)(r0 + m) * RSIZE;
#pragma unroll
        for (int c = 0; c < 8; ++c)
            wr[m][c] = *(const float4*)(row + c * 256 + lane * 4);
        wi[m] = *(const float2*)(W_in + (size_t)(r0 + m) * ISIZE + lane * 2);
    }
#pragma unroll
    for (int m = 0; m < RPW; ++m) {
#pragma unroll
        for (int c = 0; c < 8; ++c) {
            PIN(wr[m][c].x); PIN(wr[m][c].y);
            PIN(wr[m][c].z); PIN(wr[m][c].w);
        }
        PIN(wi[m].x); PIN(wi[m].y);
    }

    unsigned* counter = bar;
    unsigned* gen     = bar + 32;  // separate 128B line

    for (int t = 0; t < T_STEPS; ++t) {
        // ---- stage x[t-1] and u[t] into LDS ----
        if (t == 0) {
            ((float4*)xbuf)[tid] = make_float4(0.f, 0.f, 0.f, 0.f);
        } else {
            ((float4*)xbuf)[tid] =
                *(const float4*)(out + (size_t)(t - 1) * RSIZE + tid * 4);
        }
        if (tid < ISIZE / 4) {
            ((float4*)ubuf)[tid] =
                *(const float4*)(input + (size_t)t * ISIZE + tid * 4);
        }
        __syncthreads();

        // ---- per-wave matvec rows r0..r0+3 ----
        float4 xv[8];
#pragma unroll
        for (int c = 0; c < 8; ++c)
            xv[c] = ((const float4*)xbuf)[c * 64 + lane];
        float2 uv = ((const float2*)ubuf)[lane];

        float acc[RPW];
#pragma unroll
        for (int m = 0; m < RPW; ++m) {
            float a = wi[m].x * uv.x + wi[m].y * uv.y;
#pragma unroll
            for (int c = 0; c < 8; ++c) {
                a += wr[m][c].x * xv[c].x;
                a += wr[m][c].y * xv[c].y;
                a += wr[m][c].z * xv[c].z;
                a += wr[m][c].w * xv[c].w;
            }
#pragma unroll
            for (int off = 32; off > 0; off >>= 1)
                a += __shfl_xor(a, off, 64);
            acc[m] = a;   // every lane now holds the full row sum
        }

        // lanes 0..3 each finish one row (static acc indexing, rule #20)
        if (lane < RPW) {
            float pre = (lane == 0) ? acc[0]
                      : (lane == 1) ? acc[1]
                      : (lane == 2) ? acc[2] : acc[3];
            float xp  = xbuf[r0 + lane];
            float xn  = 0.1f * xp + 0.9f * erf_approx(pre) * invs;
            out[(size_t)t * RSIZE + r0 + lane] = xn;
        }

        if (t + 1 < T_STEPS)
            grid_barrier(counter, gen, (unsigned)gridDim.x);
    }
}

extern "C" void kernel_launch(void* const* d_in, const int* in_sizes, int n_in,
                              void* d_out, int out_size, void* d_ws,
                              size_t ws_size, hipStream_t stream) {
    const float* input = (const float*)d_in[0];
    const float* W_in  = (const float*)d_in[1];
    const float* W_res = (const float*)d_in[2];
    float*       out   = (float*)d_out;
    unsigned*    bar   = (unsigned*)d_ws;

    // barrier state must be zero at the start of every call (deterministic)
    hipMemsetAsync(bar, 0, 256, stream);

    void* args[] = {(void*)&input, (void*)&W_in, (void*)&W_res,
                    (void*)&out, (void*)&bar};
    hipError_t err = hipLaunchCooperativeKernel(
        (const void*)esn_persistent, dim3(NBLK), dim3(NTHR), args, 0, stream);
    if (err != hipSuccess) {
        // 64 blocks / 256 CUs: trivially co-resident; plain launch fallback
        esn_persistent<<<dim3(NBLK), dim3(NTHR), 0, stream>>>(
            input, W_in, W_res, out, bar);
    }
}

// Round 3
// 100090.399 us; speedup vs baseline: 1.0877x; 1.0193x over previous
//
#include <hip/hip_runtime.h>
#include <math.h>

#define T_STEPS 20000
#define RSIZE   2048
#define ISIZE   128
#define NBLK    64
#define NTHR    512                    // 8 waves/block, 1 block/CU
#define NWAVES  (NBLK * (NTHR / 64))   // 512 waves
#define RPW     (RSIZE / NWAVES)       // 4 rows per wave

// ---- cheap erf: Abramowitz-Stegun 7.1.26, |err| <= 1.5e-7 (abs) ----
__device__ __forceinline__ float erf_approx(float x) {
    float ax = fabsf(x);
    float t  = 1.0f / (1.0f + 0.3275911f * ax);
    float y  = t * (0.254829592f +
               t * (-0.284496736f +
               t * (1.421413741f +
               t * (-1.453152027f +
               t * 1.061405429f))));
    float e  = __expf(-ax * ax);
    float r  = 1.0f - y * e;
    return copysignf(r, x);
}

// ---- explicit AGPR residency (gfx950 unified RF; no MFMA in this kernel,
// so AGPRs are free storage the allocator cannot spill or rematerialize) ----
#define AGPR_W(a, v) asm volatile("v_accvgpr_write_b32 %0, %1" : "=a"(a) : "v"(v))
#define AGPR_R(v, a) asm volatile("v_accvgpr_read_b32 %0, %1" : "=v"(v) : "a"(a))

// ---- device-scope grid barrier (gen-counter; relaxed poll + acquire exit) ----
__device__ __forceinline__ void grid_barrier(unsigned* counter, unsigned* gen,
                                             unsigned nblocks) {
    __syncthreads();
    if (threadIdx.x == 0) {
        unsigned g = __hip_atomic_load(gen, __ATOMIC_RELAXED,
                                       __HIP_MEMORY_SCOPE_AGENT);
        unsigned arrived = __hip_atomic_fetch_add(counter, 1u, __ATOMIC_ACQ_REL,
                                                  __HIP_MEMORY_SCOPE_AGENT);
        if (arrived == nblocks - 1u) {
            __hip_atomic_store(counter, 0u, __ATOMIC_RELAXED,
                               __HIP_MEMORY_SCOPE_AGENT);
            __hip_atomic_store(gen, g + 1u, __ATOMIC_RELEASE,
                               __HIP_MEMORY_SCOPE_AGENT);
        } else {
            while (__hip_atomic_load(gen, __ATOMIC_RELAXED,
                                     __HIP_MEMORY_SCOPE_AGENT) == g) {
                __builtin_amdgcn_s_sleep(1);
            }
            // one acquire (cache-inv) after exit instead of per poll
            (void)__hip_atomic_load(gen, __ATOMIC_ACQUIRE,
                                    __HIP_MEMORY_SCOPE_AGENT);
        }
    }
    __syncthreads();
}

__global__ __launch_bounds__(NTHR, 2) void esn_persistent(
        const float* __restrict__ input,   // [T, 128]
        const float* __restrict__ W_in,    // [2048, 128]
        const float* __restrict__ W_res,   // [2048, 2048]
        float* __restrict__ out,           // [T, 2048]  (rows == states)
        unsigned* __restrict__ bar) {
    __shared__ float xbuf[RSIZE];   // x[t-1]
    __shared__ float ubuf[ISIZE];   // input[t]

    const int tid  = threadIdx.x;
    const int lane = tid & 63;
    const int wv   = tid >> 6;
    const int wid  = blockIdx.x * (NTHR / 64) + wv;
    const int r0   = wid * RPW;
    const float invs = 0.022097086912079608f;  // 1/sqrt(2048)

    // ---- load W once, park it in AGPRs ----
    // W_res row r, lane l holds cols {c*256 + l*4 .. +3 : c=0..7}  (32 f32)
    float a_w[RPW][32];   // every access statically indexed (fully unrolled)
    float a_wi[RPW][2];
#pragma unroll
    for (int m = 0; m < RPW; ++m) {
        const float* row = W_res + (size_t)(r0 + m) * RSIZE;
#pragma unroll
        for (int c = 0; c < 8; ++c) {
            float4 w = *(const float4*)(row + c * 256 + lane * 4);
            AGPR_W(a_w[m][c * 4 + 0], w.x);
            AGPR_W(a_w[m][c * 4 + 1], w.y);
            AGPR_W(a_w[m][c * 4 + 2], w.z);
            AGPR_W(a_w[m][c * 4 + 3], w.w);
        }
        float2 wiv = *(const float2*)(W_in + (size_t)(r0 + m) * ISIZE + lane * 2);
        AGPR_W(a_wi[m][0], wiv.x);
        AGPR_W(a_wi[m][1], wiv.y);
    }

    unsigned* counter = bar;
    unsigned* gen     = bar + 32;  // separate 128B line

    for (int t = 0; t < T_STEPS; ++t) {
        // ---- stage x[t-1] and u[t] into LDS ----
        if (t == 0) {
            ((float4*)xbuf)[tid] = make_float4(0.f, 0.f, 0.f, 0.f);
        } else {
            ((float4*)xbuf)[tid] =
                *(const float4*)(out + (size_t)(t - 1) * RSIZE + tid * 4);
        }
        if (tid < ISIZE / 4) {
            ((float4*)ubuf)[tid] =
                *(const float4*)(input + (size_t)t * ISIZE + tid * 4);
        }
        __syncthreads();

        // ---- per-wave matvec rows r0..r0+3, W streamed from AGPRs ----
        float4 xv[8];
#pragma unroll
        for (int c = 0; c < 8; ++c)
            xv[c] = ((const float4*)xbuf)[c * 64 + lane];
        float2 uv = ((const float2*)ubuf)[lane];

        float acc[RPW];
#pragma unroll
        for (int m = 0; m < RPW; ++m) {
            float w0, w1;
            AGPR_R(w0, a_wi[m][0]);
            AGPR_R(w1, a_wi[m][1]);
            float s0 = w0 * uv.x + w1 * uv.y;   // chain 0
            float s1 = 0.0f;                     // chain 1 (ILP)
#pragma unroll
            for (int c = 0; c < 8; ++c) {
                float t0, t1, t2, t3;
                AGPR_R(t0, a_w[m][c * 4 + 0]);
                AGPR_R(t1, a_w[m][c * 4 + 1]);
                AGPR_R(t2, a_w[m][c * 4 + 2]);
                AGPR_R(t3, a_w[m][c * 4 + 3]);
                s0 = fmaf(t0, xv[c].x, s0);
                s1 = fmaf(t1, xv[c].y, s1);
                s0 = fmaf(t2, xv[c].z, s0);
                s1 = fmaf(t3, xv[c].w, s1);
            }
            float a = s0 + s1;
#pragma unroll
            for (int off = 32; off > 0; off >>= 1)
                a += __shfl_xor(a, off, 64);
            acc[m] = a;   // every lane holds the full row sum
        }

        // lanes 0..3 each finish one row (static acc indexing)
        if (lane < RPW) {
            float pre = (lane == 0) ? acc[0]
                      : (lane == 1) ? acc[1]
                      : (lane == 2) ? acc[2] : acc[3];
            float xp  = xbuf[r0 + lane];
            float xn  = 0.1f * xp + 0.9f * erf_approx(pre) * invs;
            out[(size_t)t * RSIZE + r0 + lane] = xn;
        }

        if (t + 1 < T_STEPS)
            grid_barrier(counter, gen, (unsigned)gridDim.x);
    }
}

extern "C" void kernel_launch(void* const* d_in, const int* in_sizes, int n_in,
                              void* d_out, int out_size, void* d_ws,
                              size_t ws_size, hipStream_t stream) {
    const float* input = (const float*)d_in[0];
    const float* W_in  = (const float*)d_in[1];
    const float* W_res = (const float*)d_in[2];
    float*       out   = (float*)d_out;
    unsigned*    bar   = (unsigned*)d_ws;

    // barrier state must be zero at the start of every call (deterministic)
    hipMemsetAsync(bar, 0, 256, stream);

    void* args[] = {(void*)&input, (void*)&W_in, (void*)&W_res,
                    (void*)&out, (void*)&bar};
    hipError_t err = hipLaunchCooperativeKernel(
        (const void*)esn_persistent, dim3(NBLK), dim3(NTHR), args, 0, stream);
    if (err != hipSuccess) {
        // 64 blocks / 256 CUs: trivially co-resident; plain launch fallback
        esn_persistent<<<dim3(NBLK), dim3(NTHR), 0, stream>>>(
            input, W_in, W_res, out, bar);
    }
}